// Round 1
// baseline (1815.129 us; speedup 1.0000x reference)
//
#include <hip/hip_runtime.h>

// Problem constants (fixed by setup_inputs): N=4, C=32, H=W=300, P=5
#define N_B   4
#define C_F   32          // n_feats
#define H_D   300
#define W_D   300
#define HW    90000       // 300*300
#define P_P   5
#define G_G   60          // H/P
#define L_L   3600        // G*G
#define OUT_HALF 11520000 // 4*32*300*300

// One thread per output pixel (n, y, x). Computes all 32 output channels of
// BOTH convs (rgb + hsi) so the gather address math is shared.
__global__ __launch_bounds__(256)
void fused_gather_conv(const float* __restrict__ xrgb,
                       const float* __restrict__ yhsi,
                       const int*   __restrict__ corr,
                       const float* __restrict__ rgb_gamma,
                       const float* __restrict__ hsi_gamma,
                       const float* __restrict__ wR,
                       const float* __restrict__ bR,
                       const float* __restrict__ wH,
                       const float* __restrict__ bH,
                       float* __restrict__ out)
{
    int tid = blockIdx.x * blockDim.x + threadIdx.x;
    if (tid >= N_B * HW) return;
    int n   = tid / HW;
    int pix = tid - n * HW;
    int y   = pix / W_D;
    int x   = pix - y * W_D;

    const int* idx = corr + n * (L_L * 4);   // corr[0][n][.][.]

    const float* xb = xrgb + n * (C_F * HW);
    const float* yb = yhsi + n * (C_F * HW);

    float accR[32], accH[32];
    #pragma unroll
    for (int i = 0; i < 32; ++i) { accR[i] = 0.f; accH[i] = 0.f; }

    for (int k = 0; k < 4; ++k) {
        float gr = rgb_gamma[k];
        float gh = hsi_gamma[k];

        // Per-tap gathered source offsets for this channel-block k.
        int off[9];
        #pragma unroll
        for (int t = 0; t < 9; ++t) {
            int dy = t / 3 - 1, dx = t % 3 - 1;
            int yy = y + dy, xx = x + dx;
            int o = -1;
            if (yy >= 0 && yy < H_D && xx >= 0 && xx < W_D) {
                int pr = yy / P_P, pc = xx / P_P;
                int j  = pr * G_G + pc;
                int jp = (k == 0) ? j : idx[j * 4 + k];
                int py = (jp / G_G) * P_P + (yy - pr * P_P);
                int px = (jp % G_G) * P_P + (xx - pc * P_P);
                o = py * W_D + px;
            }
            off[t] = o;
        }

        for (int c = 0; c < 32; ++c) {
            // rgb image channel c: c<16 -> x_rgb[16+c], else y_hsi[c]
            // hsi image channel c: c<16 -> x_rgb[c],    else y_hsi[c-16]
            const float* srcR = (c < 16) ? (xb + (16 + c) * HW) : (yb + c * HW);
            const float* srcH = (c < 16) ? (xb + c * HW) : (yb + (c - 16) * HW);

            float vr[9], vh[9];
            #pragma unroll
            for (int t = 0; t < 9; ++t) {
                bool vld = off[t] >= 0;
                vr[t] = vld ? gr * srcR[off[t]] : 0.f;
                vh[t] = vld ? gh * srcH[off[t]] : 0.f;
            }

            // W layout: [co][cin=128][3][3]; cin = k*32 + c
            const float* wRp = wR + (k * 32 + c) * 9;  // + co*1152 + t
            const float* wHp = wH + (k * 32 + c) * 9;
            #pragma unroll
            for (int t = 0; t < 9; ++t) {
                #pragma unroll
                for (int co = 0; co < 32; ++co) {
                    accR[co] = fmaf(vr[t], wRp[co * 1152 + t], accR[co]);
                    accH[co] = fmaf(vh[t], wHp[co * 1152 + t], accH[co]);
                }
            }
        }
    }

    // Epilogue: + bias + residual, write both outputs.
    #pragma unroll
    for (int co = 0; co < 32; ++co) {
        float resR = (co < 16) ? xb[(16 + co) * HW + pix] : yb[co * HW + pix];
        float resH = (co < 16) ? xb[co * HW + pix] : yb[(co - 16) * HW + pix];
        out[(n * 32 + co) * HW + pix]            = accR[co] + bR[co] + resR;
        out[OUT_HALF + (n * 32 + co) * HW + pix] = accH[co] + bH[co] + resH;
    }
}

extern "C" void kernel_launch(void* const* d_in, const int* in_sizes, int n_in,
                              void* d_out, int out_size, void* d_ws, size_t ws_size,
                              hipStream_t stream) {
    const float* xrgb = (const float*)d_in[0];
    const float* yhsi = (const float*)d_in[1];
    const int*   corr = (const int*)d_in[2];
    const float* rg   = (const float*)d_in[3];
    const float* hg   = (const float*)d_in[4];
    const float* wR   = (const float*)d_in[5];
    const float* bR   = (const float*)d_in[6];
    const float* wH   = (const float*)d_in[7];
    const float* bH   = (const float*)d_in[8];
    float* out = (float*)d_out;

    int total = N_B * HW;
    int threads = 256;
    int blocks = (total + threads - 1) / threads;
    hipLaunchKernelGGL(fused_gather_conv, dim3(blocks), dim3(threads), 0, stream,
                       xrgb, yhsi, corr, rg, hg, wR, bR, wH, bH, out);
}

// Round 4
// 450.412 us; speedup vs baseline: 4.0299x; 4.0299x over previous
//
#include <hip/hip_runtime.h>

// N=4, C=32(n_feats), H=W=300, P=5 fixed by setup_inputs.
#define HW        90000
#define OUT_HALF  11520000
#define WPACK_OFF 92160000ull
#define WS_NEED   (92160000ull + 147456ull)

typedef short short8 __attribute__((ext_vector_type(8)));
typedef float f32x4  __attribute__((ext_vector_type(4)));

__device__ inline short f2bf(float f) {
    unsigned u = __builtin_bit_cast(unsigned, f);
    u += 0x7fff + ((u >> 16) & 1);            // RNE
    return (short)(u >> 16);
}

// ---- weight pack for mfma_f32_16x16x32_bf16 A-operand ----
// A-frag: lane l holds A[row=l&15][k = 8*(l>>4)+e], e=0..7 contiguous.
// layout: [conv][kb=4][t=9][h=2][lane=64][e=8], co = h*16 + (l&15), cin = kb*32 + 8*(l>>4)+e
__global__ __launch_bounds__(256)
void pack_weights(const float* __restrict__ wR, const float* __restrict__ wH,
                  short* __restrict__ wpack) {
    int id = blockIdx.x * 256 + threadIdx.x;   // 2*4*9*2*64*8 = 73728
    if (id >= 73728) return;
    int e    = id & 7;
    int lane = (id >> 3) & 63;
    int h    = (id >> 9) & 1;
    int t    = (id >> 10) % 9;
    int kb   = ((id >> 10) / 9) & 3;
    int conv = id / 36864;
    int co   = h * 16 + (lane & 15);
    int cin  = kb * 32 + (lane >> 4) * 8 + e;
    const float* w = conv ? wH : wR;
    wpack[id] = f2bf(w[(co * 128 + cin) * 9 + t]);
}

// ---- gather: build NHWC bf16 image [n][y][x][cin=128], LDS-free ----
__global__ __launch_bounds__(256)
void gather_img(const float* __restrict__ xrgb, const float* __restrict__ yhsi,
                const int* __restrict__ corr, const float* __restrict__ gamma,
                short* __restrict__ img, int conv) {
    int xb = blockIdx.x, y = blockIdx.y, n = blockIdx.z;
    int lane6 = threadIdx.x & 63;
    int cq    = threadIdx.x >> 6;            // 0..3
    int x = xb * 64 + lane6;
    if (x >= 300) return;
    int pr = y / 5, pc = x / 5;
    int j  = pr * 60 + pc;
    int pyi = y - pr * 5, pxi = x - pc * 5;
    const float* xb_ = xrgb + n * 32 * HW;
    const float* yb_ = yhsi + n * 32 * HW;
    const int* cr = corr + (n * 3600 + j) * 4;
    short8* dst = (short8*)(img + ((size_t)n * HW + y * 300 + x) * 128);   // n offset FIX
    #pragma unroll
    for (int r = 0; r < 4; ++r) {
        int c16 = cq + r * 4;                // channel chunk 0..15
        int k   = c16 >> 2;                  // gather slot
        int jp  = (k == 0) ? j : cr[k];
        int soff = ((jp / 60) * 5 + pyi) * 300 + (jp % 60) * 5 + pxi;
        float g = gamma[k];
        int cbase = (c16 & 3) * 8;           // source channel base within 32
        short8 v;
        #pragma unroll
        for (int e = 0; e < 8; ++e) {
            int c = cbase + e;
            const float* src;
            if (conv == 0) src = (c < 16) ? (xb_ + (16 + c) * HW) : (yb_ + c * HW);
            else           src = (c < 16) ? (xb_ + c * HW) : (yb_ + (c - 16) * HW);
            v[e] = f2bf(src[soff] * g);
        }
        dst[c16] = v;
    }
}

// ---- conv: 12x16 output tile, 4 waves x 3 rows x 2 co-halves, mfma 16x16x32 ----
__global__ __launch_bounds__(256, 2)
void conv_mfma(const short* __restrict__ img, const short* __restrict__ wpack,
               const float* __restrict__ xrgb, const float* __restrict__ yhsi,
               const float* __restrict__ bias, float* __restrict__ out, int conv) {
    __shared__ alignas(16) char lds[14 * 18 * 256];   // 64512 B halo tile, NHWC
    int tile = blockIdx.x;
    int n = blockIdx.y;
    int ty = tile / 19, tx = tile - ty * 19;
    int y0 = ty * 12, x0 = tx * 16;
    int tid = threadIdx.x;

    const short* imgn = img + (size_t)n * HW * 128;   // n offset FIX

    // stage halo tile (14x18 px x 128 cin) with XOR swizzle on 16B chunks
    for (int ch = tid; ch < 14 * 18 * 16; ch += 256) {
        int pix = ch >> 4, c16 = ch & 15;
        int hr = pix / 18, hc = pix - hr * 18;
        int gy = y0 + hr - 1, gx = x0 + hc - 1;
        short8 v = {0, 0, 0, 0, 0, 0, 0, 0};
        if (gy >= 0 && gy < 300 && gx >= 0 && gx < 300)
            v = *(const short8*)(imgn + (gy * 300 + gx) * 128 + c16 * 8);
        int lin = pix * 256 + c16 * 16;
        *(short8*)(lds + (lin ^ ((hc & 7) << 4))) = v;
    }
    __syncthreads();

    int wave = tid >> 6, lane = tid & 63;
    int l15 = lane & 15, lh = lane >> 4;     // lh in 0..3

    f32x4 acc[3][2];
    #pragma unroll
    for (int g = 0; g < 3; ++g)
        #pragma unroll
        for (int h = 0; h < 2; ++h)
            acc[g][h] = (f32x4){0.f, 0.f, 0.f, 0.f};

    const short* wp = wpack + conv * 36864;

    for (int kb = 0; kb < 4; ++kb) {
        #pragma unroll
        for (int t = 0; t < 9; ++t) {
            int dy = t / 3 - 1, dx = t % 3 - 1;
            short8 a0 = *(const short8*)(wp + ((((kb * 9 + t) * 2 + 0) * 64) + lane) * 8);
            short8 a1 = *(const short8*)(wp + ((((kb * 9 + t) * 2 + 1) * 64) + lane) * 8);
            #pragma unroll
            for (int g = 0; g < 3; ++g) {
                int r  = wave * 3 + g;
                int hr = r + dy + 1;
                int hc = l15 + dx + 1;
                int lin = (hr * 18 + hc) * 256 + kb * 64 + lh * 16;
                short8 b = *(const short8*)(lds + (lin ^ ((hc & 7) << 4)));
                acc[g][0] = __builtin_amdgcn_mfma_f32_16x16x32_bf16(a0, b, acc[g][0], 0, 0, 0);
                acc[g][1] = __builtin_amdgcn_mfma_f32_16x16x32_bf16(a1, b, acc[g][1], 0, 0, 0);
            }
        }
    }

    // epilogue: D col(pixel)=lane&15, row(co within half)=(lane>>4)*4+reg
    const float* xb_ = xrgb + n * 32 * HW;
    const float* yb_ = yhsi + n * 32 * HW;
    #pragma unroll
    for (int g = 0; g < 3; ++g) {
        int gy = y0 + wave * 3 + g;
        int gx = x0 + l15;
        if (gx < 300) {
            int pixo = gy * 300 + gx;
            #pragma unroll
            for (int h = 0; h < 2; ++h) {
                #pragma unroll
                for (int reg = 0; reg < 4; ++reg) {
                    int co = h * 16 + lh * 4 + reg;
                    float res;
                    if (conv == 0) res = (co < 16) ? xb_[(16 + co) * HW + pixo] : yb_[co * HW + pixo];
                    else           res = (co < 16) ? xb_[co * HW + pixo] : yb_[(co - 16) * HW + pixo];
                    out[conv * OUT_HALF + (n * 32 + co) * HW + pixo] = acc[g][h][reg] + bias[co] + res;
                }
            }
        }
    }
}

// ---- fallback (round-1 kernel) if ws too small ----
__global__ __launch_bounds__(256)
void fused_gather_conv(const float* __restrict__ xrgb, const float* __restrict__ yhsi,
                       const int* __restrict__ corr, const float* __restrict__ rgb_gamma,
                       const float* __restrict__ hsi_gamma, const float* __restrict__ wR,
                       const float* __restrict__ bR, const float* __restrict__ wH,
                       const float* __restrict__ bH, float* __restrict__ out) {
    int tid = blockIdx.x * blockDim.x + threadIdx.x;
    if (tid >= 4 * HW) return;
    int n = tid / HW, pix = tid - n * HW;
    int y = pix / 300, x = pix - y * 300;
    const int* idx = corr + n * (3600 * 4);
    const float* xb = xrgb + n * (32 * HW);
    const float* yb = yhsi + n * (32 * HW);
    float accR[32], accH[32];
    #pragma unroll
    for (int i = 0; i < 32; ++i) { accR[i] = 0.f; accH[i] = 0.f; }
    for (int k = 0; k < 4; ++k) {
        float gr = rgb_gamma[k], gh = hsi_gamma[k];
        int off[9];
        #pragma unroll
        for (int t = 0; t < 9; ++t) {
            int dy = t / 3 - 1, dx = t % 3 - 1;
            int yy = y + dy, xx = x + dx;
            int o = -1;
            if (yy >= 0 && yy < 300 && xx >= 0 && xx < 300) {
                int pr = yy / 5, pc = xx / 5;
                int j = pr * 60 + pc;
                int jp = (k == 0) ? j : idx[j * 4 + k];
                o = ((jp / 60) * 5 + (yy - pr * 5)) * 300 + (jp % 60) * 5 + (xx - pc * 5);
            }
            off[t] = o;
        }
        for (int c = 0; c < 32; ++c) {
            const float* srcR = (c < 16) ? (xb + (16 + c) * HW) : (yb + c * HW);
            const float* srcH = (c < 16) ? (xb + c * HW) : (yb + (c - 16) * HW);
            float vr[9], vh[9];
            #pragma unroll
            for (int t = 0; t < 9; ++t) {
                bool vld = off[t] >= 0;
                vr[t] = vld ? gr * srcR[off[t]] : 0.f;
                vh[t] = vld ? gh * srcH[off[t]] : 0.f;
            }
            const float* wRp = wR + (k * 32 + c) * 9;
            const float* wHp = wH + (k * 32 + c) * 9;
            #pragma unroll
            for (int t = 0; t < 9; ++t)
                #pragma unroll
                for (int co = 0; co < 32; ++co) {
                    accR[co] = fmaf(vr[t], wRp[co * 1152 + t], accR[co]);
                    accH[co] = fmaf(vh[t], wHp[co * 1152 + t], accH[co]);
                }
        }
    }
    #pragma unroll
    for (int co = 0; co < 32; ++co) {
        float resR = (co < 16) ? xb[(16 + co) * HW + pix] : yb[co * HW + pix];
        float resH = (co < 16) ? xb[co * HW + pix] : yb[(co - 16) * HW + pix];
        out[(n * 32 + co) * HW + pix]            = accR[co] + bR[co] + resR;
        out[OUT_HALF + (n * 32 + co) * HW + pix] = accH[co] + bH[co] + resH;
    }
}

extern "C" void kernel_launch(void* const* d_in, const int* in_sizes, int n_in,
                              void* d_out, int out_size, void* d_ws, size_t ws_size,
                              hipStream_t stream) {
    const float* xrgb = (const float*)d_in[0];
    const float* yhsi = (const float*)d_in[1];
    const int*   corr = (const int*)d_in[2];
    const float* rg   = (const float*)d_in[3];
    const float* hg   = (const float*)d_in[4];
    const float* wR   = (const float*)d_in[5];
    const float* bR   = (const float*)d_in[6];
    const float* wH   = (const float*)d_in[7];
    const float* bH   = (const float*)d_in[8];
    float* out = (float*)d_out;

    if (ws_size >= WS_NEED) {
        short* img   = (short*)d_ws;
        short* wpack = (short*)((char*)d_ws + WPACK_OFF);
        hipLaunchKernelGGL(pack_weights, dim3(288), dim3(256), 0, stream, wR, wH, wpack);
        hipLaunchKernelGGL(gather_img, dim3(5, 300, 4), dim3(256), 0, stream,
                           xrgb, yhsi, corr, rg, img, 0);
        hipLaunchKernelGGL(conv_mfma, dim3(475, 4), dim3(256), 0, stream,
                           img, wpack, xrgb, yhsi, bR, out, 0);
        hipLaunchKernelGGL(gather_img, dim3(5, 300, 4), dim3(256), 0, stream,
                           xrgb, yhsi, corr, hg, img, 1);
        hipLaunchKernelGGL(conv_mfma, dim3(475, 4), dim3(256), 0, stream,
                           img, wpack, xrgb, yhsi, bH, out, 1);
    } else {
        int total = 4 * HW;
        hipLaunchKernelGGL(fused_gather_conv, dim3((total + 255) / 256), dim3(256), 0, stream,
                           xrgb, yhsi, corr, rg, hg, wR, bR, wH, bH, out);
    }
}

// Round 5
// 222.227 us; speedup vs baseline: 8.1679x; 2.0268x over previous
//
#include <hip/hip_runtime.h>

// N=4, C=32(n_feats), H=W=300, P=5 fixed by setup_inputs.
#define HW        90000
#define OUT_HALF  11520000
#define CMB_SHORTS ((size_t)4 * HW * 64)          // 23.04M shorts = 46.08 MB
#define WPACK_OFF  46080000ull
#define WS_NEED    (46080000ull + 147456ull)

typedef short short8 __attribute__((ext_vector_type(8)));
typedef float f32x4  __attribute__((ext_vector_type(4)));

__device__ inline short f2bf(float f) {
    unsigned u = __builtin_bit_cast(unsigned, f);
    u += 0x7fff + ((u >> 16) & 1);            // RNE
    return (short)(u >> 16);
}

// ---- weight pack for mfma_f32_16x16x32_bf16 A-operand, gamma folded in ----
// A-frag: lane l holds A[row=l&15][k = 8*(l>>4)+e], e=0..7 contiguous.
// layout: [conv][kb=4][t=9][h=2][lane=64][e=8], co = h*16+(l&15), cin = kb*32+8*(l>>4)+e
__global__ __launch_bounds__(256)
void pack_weights(const float* __restrict__ wR, const float* __restrict__ wH,
                  const float* __restrict__ rg, const float* __restrict__ hg,
                  short* __restrict__ wpack) {
    int id = blockIdx.x * 256 + threadIdx.x;   // 2*4*9*2*64*8 = 73728
    if (id >= 73728) return;
    int e    = id & 7;
    int lane = (id >> 3) & 63;
    int h    = (id >> 9) & 1;
    int t    = (id >> 10) % 9;
    int kb   = ((id >> 10) / 9) & 3;
    int conv = id / 36864;
    int co   = h * 16 + (lane & 15);
    int cin  = kb * 32 + (lane >> 4) * 8 + e;
    const float* w = conv ? wH : wR;
    const float* g = conv ? hg : rg;
    wpack[id] = f2bf(w[(co * 128 + cin) * 9 + t] * g[cin >> 5]);
}

// ---- NCHW f32 -> NHWC bf16 "combined" image: [n][y][x][cc=64] ----
// cc 0..15: xrgb[16+cc] | 16..31: yhsi[cc] | 32..47: xrgb[cc-32] | 48..63: yhsi[cc-48]
// (first 32 = conv0 source channels, last 32 = conv1 source channels)
__global__ __launch_bounds__(256)
void nchw2nhwc(const float* __restrict__ xrgb, const float* __restrict__ yhsi,
               short* __restrict__ cmb) {
    int wave = threadIdx.x >> 6, lane = threadIdx.x & 63;
    if (lane >= 60) return;
    int y = blockIdx.y * 4 + wave;
    int x = blockIdx.x * 60 + lane;
    int n = blockIdx.z;
    const float* xb = xrgb + n * 32 * HW + y * 300 + x;
    const float* yb = yhsi + n * 32 * HW + y * 300 + x;
    short* dst = (short*)(cmb + ((size_t)n * HW + y * 300 + x) * 64);
    #pragma unroll
    for (int q = 0; q < 8; ++q) {
        short8 v;
        #pragma unroll
        for (int e = 0; e < 8; ++e) {
            int cc = q * 8 + e;
            const float* s;
            if (cc < 16)      s = xb + (16 + cc) * HW;
            else if (cc < 32) s = yb + cc * HW;
            else if (cc < 48) s = xb + (cc - 32) * HW;
            else              s = yb + (cc - 48) * HW;
            v[e] = f2bf(*s);
        }
        *(short8*)(dst + q * 8) = v;
    }
}

// ---- conv: 12x16 output tile, gather fused into LDS staging, mfma 16x16x32 ----
__global__ __launch_bounds__(256, 2)
void conv_mfma(const short* __restrict__ combined, const short* __restrict__ wpack,
               const int* __restrict__ corr,
               const float* __restrict__ xrgb, const float* __restrict__ yhsi,
               const float* __restrict__ bias, float* __restrict__ out, int conv) {
    __shared__ alignas(16) char lds[14 * 18 * 256];   // 64512 B halo tile
    int tile = blockIdx.x;
    int n = blockIdx.y;
    int ty = tile / 19, tx = tile - ty * 19;
    int y0 = ty * 12, x0 = tx * 16;
    int tid = threadIdx.x;

    const short* cmb = combined + (size_t)n * HW * 64;

    // stage halo (14x18 px), gathering on the fly: piece = (pixel, slot k) -> 64B copy
    for (int p = tid; p < 252 * 4; p += 256) {
        int pix = p >> 2, k = p & 3;
        int hr = pix / 18, hc = pix - hr * 18;
        int gy = y0 + hr - 1, gx = x0 + hc - 1;
        short8 v0 = {0,0,0,0,0,0,0,0}, v1 = v0, v2 = v0, v3 = v0;
        if (gy >= 0 && gy < 300 && gx >= 0 && gx < 300) {
            int pr = gy / 5, pc = gx / 5;
            int j  = pr * 60 + pc;
            int jp = (k == 0) ? j : corr[(n * 3600 + j) * 4 + k];
            int soff = ((jp / 60) * 5 + (gy - pr * 5)) * 300 + (jp % 60) * 5 + (gx - pc * 5);
            const short8* s = (const short8*)(cmb + (size_t)soff * 64 + conv * 32);
            v0 = s[0]; v1 = s[1]; v2 = s[2]; v3 = s[3];
        }
        int base = pix * 256 + k * 64;
        int swz  = (hc & 7) << 4;
        *(short8*)(lds + ((base +  0) ^ swz)) = v0;
        *(short8*)(lds + ((base + 16) ^ swz)) = v1;
        *(short8*)(lds + ((base + 32) ^ swz)) = v2;
        *(short8*)(lds + ((base + 48) ^ swz)) = v3;
    }
    __syncthreads();

    int wave = tid >> 6, lane = tid & 63;
    int l15 = lane & 15, lh = lane >> 4;     // lh in 0..3

    f32x4 acc[3][2];
    #pragma unroll
    for (int g = 0; g < 3; ++g)
        #pragma unroll
        for (int h = 0; h < 2; ++h)
            acc[g][h] = (f32x4){0.f, 0.f, 0.f, 0.f};

    const short* wp = wpack + conv * 36864;

    for (int kb = 0; kb < 4; ++kb) {
        #pragma unroll
        for (int t = 0; t < 9; ++t) {
            int dy = t / 3 - 1, dx = t % 3 - 1;
            short8 a0 = *(const short8*)(wp + ((((kb * 9 + t) * 2 + 0) * 64) + lane) * 8);
            short8 a1 = *(const short8*)(wp + ((((kb * 9 + t) * 2 + 1) * 64) + lane) * 8);
            #pragma unroll
            for (int g = 0; g < 3; ++g) {
                int r  = wave * 3 + g;
                int hr = r + dy + 1;
                int hc = l15 + dx + 1;
                int lin = (hr * 18 + hc) * 256 + kb * 64 + lh * 16;
                short8 b = *(const short8*)(lds + (lin ^ ((hc & 7) << 4)));
                acc[g][0] = __builtin_amdgcn_mfma_f32_16x16x32_bf16(a0, b, acc[g][0], 0, 0, 0);
                acc[g][1] = __builtin_amdgcn_mfma_f32_16x16x32_bf16(a1, b, acc[g][1], 0, 0, 0);
            }
        }
    }

    // epilogue: D col(pixel)=lane&15, row(co within half)=(lane>>4)*4+reg
    const float* xb_ = xrgb + n * 32 * HW;
    const float* yb_ = yhsi + n * 32 * HW;
    #pragma unroll
    for (int g = 0; g < 3; ++g) {
        int gy = y0 + wave * 3 + g;
        int gx = x0 + l15;
        if (gx < 300) {
            int pixo = gy * 300 + gx;
            #pragma unroll
            for (int h = 0; h < 2; ++h) {
                #pragma unroll
                for (int reg = 0; reg < 4; ++reg) {
                    int co = h * 16 + lh * 4 + reg;
                    float res;
                    if (conv == 0) res = (co < 16) ? xb_[(16 + co) * HW + pixo] : yb_[co * HW + pixo];
                    else           res = (co < 16) ? xb_[co * HW + pixo] : yb_[(co - 16) * HW + pixo];
                    out[conv * OUT_HALF + (n * 32 + co) * HW + pixo] = acc[g][h][reg] + bias[co] + res;
                }
            }
        }
    }
}

// ---- fallback (round-1 kernel) if ws too small ----
__global__ __launch_bounds__(256)
void fused_gather_conv(const float* __restrict__ xrgb, const float* __restrict__ yhsi,
                       const int* __restrict__ corr, const float* __restrict__ rgb_gamma,
                       const float* __restrict__ hsi_gamma, const float* __restrict__ wR,
                       const float* __restrict__ bR, const float* __restrict__ wH,
                       const float* __restrict__ bH, float* __restrict__ out) {
    int tid = blockIdx.x * blockDim.x + threadIdx.x;
    if (tid >= 4 * HW) return;
    int n = tid / HW, pix = tid - n * HW;
    int y = pix / 300, x = pix - y * 300;
    const int* idx = corr + n * (3600 * 4);
    const float* xb = xrgb + n * (32 * HW);
    const float* yb = yhsi + n * (32 * HW);
    float accR[32], accH[32];
    #pragma unroll
    for (int i = 0; i < 32; ++i) { accR[i] = 0.f; accH[i] = 0.f; }
    for (int k = 0; k < 4; ++k) {
        float gr = rgb_gamma[k], gh = hsi_gamma[k];
        int off[9];
        #pragma unroll
        for (int t = 0; t < 9; ++t) {
            int dy = t / 3 - 1, dx = t % 3 - 1;
            int yy = y + dy, xx = x + dx;
            int o = -1;
            if (yy >= 0 && yy < 300 && xx >= 0 && xx < 300) {
                int pr = yy / 5, pc = xx / 5;
                int j = pr * 60 + pc;
                int jp = (k == 0) ? j : idx[j * 4 + k];
                o = ((jp / 60) * 5 + (yy - pr * 5)) * 300 + (jp % 60) * 5 + (xx - pc * 5);
            }
            off[t] = o;
        }
        for (int c = 0; c < 32; ++c) {
            const float* srcR = (c < 16) ? (xb + (16 + c) * HW) : (yb + c * HW);
            const float* srcH = (c < 16) ? (xb + c * HW) : (yb + (c - 16) * HW);
            float vr[9], vh[9];
            #pragma unroll
            for (int t = 0; t < 9; ++t) {
                bool vld = off[t] >= 0;
                vr[t] = vld ? gr * srcR[off[t]] : 0.f;
                vh[t] = vld ? gh * srcH[off[t]] : 0.f;
            }
            const float* wRp = wR + (k * 32 + c) * 9;
            const float* wHp = wH + (k * 32 + c) * 9;
            #pragma unroll
            for (int t = 0; t < 9; ++t)
                #pragma unroll
                for (int co = 0; co < 32; ++co) {
                    accR[co] = fmaf(vr[t], wRp[co * 1152 + t], accR[co]);
                    accH[co] = fmaf(vh[t], wHp[co * 1152 + t], accH[co]);
                }
        }
    }
    #pragma unroll
    for (int co = 0; co < 32; ++co) {
        float resR = (co < 16) ? xb[(16 + co) * HW + pix] : yb[co * HW + pix];
        float resH = (co < 16) ? xb[co * HW + pix] : yb[(co - 16) * HW + pix];
        out[(n * 32 + co) * HW + pix]            = accR[co] + bR[co] + resR;
        out[OUT_HALF + (n * 32 + co) * HW + pix] = accH[co] + bH[co] + resH;
    }
}

extern "C" void kernel_launch(void* const* d_in, const int* in_sizes, int n_in,
                              void* d_out, int out_size, void* d_ws, size_t ws_size,
                              hipStream_t stream) {
    const float* xrgb = (const float*)d_in[0];
    const float* yhsi = (const float*)d_in[1];
    const int*   corr = (const int*)d_in[2];
    const float* rg   = (const float*)d_in[3];
    const float* hg   = (const float*)d_in[4];
    const float* wR   = (const float*)d_in[5];
    const float* bR   = (const float*)d_in[6];
    const float* wH   = (const float*)d_in[7];
    const float* bH   = (const float*)d_in[8];
    float* out = (float*)d_out;

    if (ws_size >= WS_NEED) {
        short* cmb   = (short*)d_ws;
        short* wpack = (short*)((char*)d_ws + WPACK_OFF);
        hipLaunchKernelGGL(pack_weights, dim3(288), dim3(256), 0, stream, wR, wH, rg, hg, wpack);
        hipLaunchKernelGGL(nchw2nhwc, dim3(5, 75, 4), dim3(256), 0, stream, xrgb, yhsi, cmb);
        hipLaunchKernelGGL(conv_mfma, dim3(475, 4), dim3(256), 0, stream,
                           cmb, wpack, corr, xrgb, yhsi, bR, out, 0);
        hipLaunchKernelGGL(conv_mfma, dim3(475, 4), dim3(256), 0, stream,
                           cmb, wpack, corr, xrgb, yhsi, bH, out, 1);
    } else {
        int total = 4 * HW;
        hipLaunchKernelGGL(fused_gather_conv, dim3((total + 255) / 256), dim3(256), 0, stream,
                           xrgb, yhsi, corr, rg, hg, wR, bR, wH, bH, out);
    }
}

// Round 6
// 197.312 us; speedup vs baseline: 9.1993x; 1.1263x over previous
//
#include <hip/hip_runtime.h>

// N=4, C=32(n_feats), H=W=300, P=5 fixed by setup_inputs.
#define HW        90000
#define OUT_HALF  11520000
#define WPACK_OFF  46080000ull
#define WS_NEED    (46080000ull + 147456ull)

typedef short short8 __attribute__((ext_vector_type(8)));
typedef float f32x4  __attribute__((ext_vector_type(4)));

__device__ inline short f2bf(float f) {
    unsigned u = __builtin_bit_cast(unsigned, f);
    u += 0x7fff + ((u >> 16) & 1);            // RNE
    return (short)(u >> 16);
}

// ---- weight pack for mfma_f32_16x16x32_bf16 A-operand, gamma folded in ----
// A-frag: lane l holds A[row=l&15][k = 8*(l>>4)+e], e=0..7 contiguous.
// layout: [conv][kb=4][t=9][h=2][lane=64][e=8], co = h*16+(l&15), cin = kb*32+8*(l>>4)+e
__global__ __launch_bounds__(256)
void pack_weights(const float* __restrict__ wR, const float* __restrict__ wH,
                  const float* __restrict__ rg, const float* __restrict__ hg,
                  short* __restrict__ wpack) {
    int id = blockIdx.x * 256 + threadIdx.x;   // 2*4*9*2*64*8 = 73728
    if (id >= 73728) return;
    int e    = id & 7;
    int lane = (id >> 3) & 63;
    int h    = (id >> 9) & 1;
    int t    = (id >> 10) % 9;
    int kb   = ((id >> 10) / 9) & 3;
    int conv = id / 36864;
    int co   = h * 16 + (lane & 15);
    int cin  = kb * 32 + (lane >> 4) * 8 + e;
    const float* w = conv ? wH : wR;
    const float* g = conv ? hg : rg;
    wpack[id] = f2bf(w[(co * 128 + cin) * 9 + t] * g[cin >> 5]);
}

// ---- NCHW f32 -> NHWC bf16 "combined" image: [n][y][x][cc=64] ----
// cc 0..15: xrgb[16+cc] | 16..31: yhsi[cc] | 32..47: xrgb[cc-32] | 48..63: yhsi[cc-48]
__global__ __launch_bounds__(256)
void nchw2nhwc(const float* __restrict__ xrgb, const float* __restrict__ yhsi,
               short* __restrict__ cmb) {
    int wave = threadIdx.x >> 6, lane = threadIdx.x & 63;
    if (lane >= 60) return;
    int y = blockIdx.y * 4 + wave;
    int x = blockIdx.x * 60 + lane;
    int n = blockIdx.z;
    const float* xb = xrgb + n * 32 * HW + y * 300 + x;
    const float* yb = yhsi + n * 32 * HW + y * 300 + x;
    short* dst = (short*)(cmb + ((size_t)n * HW + y * 300 + x) * 64);
    #pragma unroll
    for (int q = 0; q < 8; ++q) {
        short8 v;
        #pragma unroll
        for (int e = 0; e < 8; ++e) {
            int cc = q * 8 + e;
            const float* s;
            if (cc < 16)      s = xb + (16 + cc) * HW;
            else if (cc < 32) s = yb + cc * HW;
            else if (cc < 48) s = xb + (cc - 32) * HW;
            else              s = yb + (cc - 48) * HW;
            v[e] = f2bf(*s);
        }
        *(short8*)(dst + q * 8) = v;
    }
}

// ---- conv: 8x16 output tile, halo 10x18, both convs in grid.z, 3 blocks/CU ----
__global__ __launch_bounds__(256, 3)
void conv_mfma(const short* __restrict__ combined, const short* __restrict__ wpack,
               const int* __restrict__ corr,
               const float* __restrict__ xrgb, const float* __restrict__ yhsi,
               const float* __restrict__ bR, const float* __restrict__ bH,
               float* __restrict__ out) {
    __shared__ alignas(16) char lds[180 * 256];   // 46080 B: 10x18 px * 4 slots * 64B
    int tile = blockIdx.x;
    int n = blockIdx.y;
    int conv = blockIdx.z;
    int ty = tile / 19, tx = tile - ty * 19;
    int y0 = ty * 8, x0 = tx * 16;
    int tid = threadIdx.x;

    const short* cmb = combined + (size_t)n * HW * 64;

    // stage halo, k-major piece order: p = k*180 + pix -> wave reads 64 consecutive px
    for (int p = tid; p < 720; p += 256) {
        int k = p / 180, pix = p - k * 180;
        int hr = pix / 18, hc = pix - hr * 18;
        int gy = y0 + hr - 1, gx = x0 + hc - 1;
        short8 v0 = {0,0,0,0,0,0,0,0}, v1 = v0, v2 = v0, v3 = v0;
        if (gy >= 0 && gy < 300 && gx >= 0 && gx < 300) {
            int pr = gy / 5, pc = gx / 5;
            int j  = pr * 60 + pc;
            int jp = (k == 0) ? j : corr[(n * 3600 + j) * 4 + k];
            int soff = ((jp / 60) * 5 + (gy - pr * 5)) * 300 + (jp % 60) * 5 + (gx - pc * 5);
            const short8* s = (const short8*)(cmb + (size_t)soff * 64 + conv * 32);
            v0 = s[0]; v1 = s[1]; v2 = s[2]; v3 = s[3];
        }
        int base = pix * 256 + k * 64;
        int swz  = (hc & 7) << 4;
        *(short8*)(lds + ((base +  0) ^ swz)) = v0;
        *(short8*)(lds + ((base + 16) ^ swz)) = v1;
        *(short8*)(lds + ((base + 32) ^ swz)) = v2;
        *(short8*)(lds + ((base + 48) ^ swz)) = v3;
    }
    __syncthreads();

    int wave = tid >> 6, lane = tid & 63;
    int l15 = lane & 15, lh = lane >> 4;     // lh in 0..3

    f32x4 acc[2][2];
    #pragma unroll
    for (int g = 0; g < 2; ++g)
        #pragma unroll
        for (int h = 0; h < 2; ++h)
            acc[g][h] = (f32x4){0.f, 0.f, 0.f, 0.f};

    const short* wp = wpack + conv * 36864;

    for (int kb = 0; kb < 4; ++kb) {
        #pragma unroll
        for (int t = 0; t < 9; ++t) {
            int dy = t / 3 - 1, dx = t % 3 - 1;
            short8 a0 = *(const short8*)(wp + ((((kb * 9 + t) * 2 + 0) * 64) + lane) * 8);
            short8 a1 = *(const short8*)(wp + ((((kb * 9 + t) * 2 + 1) * 64) + lane) * 8);
            #pragma unroll
            for (int g = 0; g < 2; ++g) {
                int r  = wave * 2 + g;
                int hr = r + dy + 1;
                int hc = l15 + dx + 1;
                int lin = (hr * 18 + hc) * 256 + kb * 64 + lh * 16;
                short8 b = *(const short8*)(lds + (lin ^ ((hc & 7) << 4)));
                acc[g][0] = __builtin_amdgcn_mfma_f32_16x16x32_bf16(a0, b, acc[g][0], 0, 0, 0);
                acc[g][1] = __builtin_amdgcn_mfma_f32_16x16x32_bf16(a1, b, acc[g][1], 0, 0, 0);
            }
        }
    }

    // epilogue: D col(pixel)=lane&15, row(co within half)=(lane>>4)*4+reg
    const float* xb_ = xrgb + n * 32 * HW;
    const float* yb_ = yhsi + n * 32 * HW;
    const float* bias = conv ? bH : bR;
    #pragma unroll
    for (int g = 0; g < 2; ++g) {
        int gy = y0 + wave * 2 + g;
        int gx = x0 + l15;
        if (gy < 300 && gx < 300) {
            int pixo = gy * 300 + gx;
            #pragma unroll
            for (int h = 0; h < 2; ++h) {
                #pragma unroll
                for (int reg = 0; reg < 4; ++reg) {
                    int co = h * 16 + lh * 4 + reg;
                    float res;
                    if (conv == 0) res = (co < 16) ? xb_[(16 + co) * HW + pixo] : yb_[co * HW + pixo];
                    else           res = (co < 16) ? xb_[co * HW + pixo] : yb_[(co - 16) * HW + pixo];
                    out[conv * OUT_HALF + (n * 32 + co) * HW + pixo] = acc[g][h][reg] + bias[co] + res;
                }
            }
        }
    }
}

// ---- fallback (round-1 kernel) if ws too small ----
__global__ __launch_bounds__(256)
void fused_gather_conv(const float* __restrict__ xrgb, const float* __restrict__ yhsi,
                       const int* __restrict__ corr, const float* __restrict__ rgb_gamma,
                       const float* __restrict__ hsi_gamma, const float* __restrict__ wR,
                       const float* __restrict__ bR, const float* __restrict__ wH,
                       const float* __restrict__ bH, float* __restrict__ out) {
    int tid = blockIdx.x * blockDim.x + threadIdx.x;
    if (tid >= 4 * HW) return;
    int n = tid / HW, pix = tid - n * HW;
    int y = pix / 300, x = pix - y * 300;
    const int* idx = corr + n * (3600 * 4);
    const float* xb = xrgb + n * (32 * HW);
    const float* yb = yhsi + n * (32 * HW);
    float accR[32], accH[32];
    #pragma unroll
    for (int i = 0; i < 32; ++i) { accR[i] = 0.f; accH[i] = 0.f; }
    for (int k = 0; k < 4; ++k) {
        float gr = rgb_gamma[k], gh = hsi_gamma[k];
        int off[9];
        #pragma unroll
        for (int t = 0; t < 9; ++t) {
            int dy = t / 3 - 1, dx = t % 3 - 1;
            int yy = y + dy, xx = x + dx;
            int o = -1;
            if (yy >= 0 && yy < 300 && xx >= 0 && xx < 300) {
                int pr = yy / 5, pc = xx / 5;
                int j = pr * 60 + pc;
                int jp = (k == 0) ? j : idx[j * 4 + k];
                o = ((jp / 60) * 5 + (yy - pr * 5)) * 300 + (jp % 60) * 5 + (xx - pc * 5);
            }
            off[t] = o;
        }
        for (int c = 0; c < 32; ++c) {
            const float* srcR = (c < 16) ? (xb + (16 + c) * HW) : (yb + c * HW);
            const float* srcH = (c < 16) ? (xb + c * HW) : (yb + (c - 16) * HW);
            float vr[9], vh[9];
            #pragma unroll
            for (int t = 0; t < 9; ++t) {
                bool vld = off[t] >= 0;
                vr[t] = vld ? gr * srcR[off[t]] : 0.f;
                vh[t] = vld ? gh * srcH[off[t]] : 0.f;
            }
            const float* wRp = wR + (k * 32 + c) * 9;
            const float* wHp = wH + (k * 32 + c) * 9;
            #pragma unroll
            for (int t = 0; t < 9; ++t)
                #pragma unroll
                for (int co = 0; co < 32; ++co) {
                    accR[co] = fmaf(vr[t], wRp[co * 1152 + t], accR[co]);
                    accH[co] = fmaf(vh[t], wHp[co * 1152 + t], accH[co]);
                }
        }
    }
    #pragma unroll
    for (int co = 0; co < 32; ++co) {
        float resR = (co < 16) ? xb[(16 + co) * HW + pix] : yb[co * HW + pix];
        float resH = (co < 16) ? xb[co * HW + pix] : yb[(co - 16) * HW + pix];
        out[(n * 32 + co) * HW + pix]            = accR[co] + bR[co] + resR;
        out[OUT_HALF + (n * 32 + co) * HW + pix] = accH[co] + bH[co] + resH;
    }
}

extern "C" void kernel_launch(void* const* d_in, const int* in_sizes, int n_in,
                              void* d_out, int out_size, void* d_ws, size_t ws_size,
                              hipStream_t stream) {
    const float* xrgb = (const float*)d_in[0];
    const float* yhsi = (const float*)d_in[1];
    const int*   corr = (const int*)d_in[2];
    const float* rg   = (const float*)d_in[3];
    const float* hg   = (const float*)d_in[4];
    const float* wR   = (const float*)d_in[5];
    const float* bR   = (const float*)d_in[6];
    const float* wH   = (const float*)d_in[7];
    const float* bH   = (const float*)d_in[8];
    float* out = (float*)d_out;

    if (ws_size >= WS_NEED) {
        short* cmb   = (short*)d_ws;
        short* wpack = (short*)((char*)d_ws + WPACK_OFF);
        hipLaunchKernelGGL(pack_weights, dim3(288), dim3(256), 0, stream, wR, wH, rg, hg, wpack);
        hipLaunchKernelGGL(nchw2nhwc, dim3(5, 75, 4), dim3(256), 0, stream, xrgb, yhsi, cmb);
        hipLaunchKernelGGL(conv_mfma, dim3(722, 4, 2), dim3(256), 0, stream,
                           cmb, wpack, corr, xrgb, yhsi, bR, bH, out);
    } else {
        int total = 4 * HW;
        hipLaunchKernelGGL(fused_gather_conv, dim3((total + 255) / 256), dim3(256), 0, stream,
                           xrgb, yhsi, corr, rg, hg, wR, bR, wH, bH, out);
    }
}

// Round 7
// 180.385 us; speedup vs baseline: 10.0625x; 1.0938x over previous
//
#include <hip/hip_runtime.h>

// N=4, C=32(n_feats), H=W=300, P=5 fixed by setup_inputs.
#define HW        90000
#define OUT_HALF  11520000
#define WPACK_OFF  46080000ull
#define WS_NEED    (46080000ull + 147456ull)

typedef short short8 __attribute__((ext_vector_type(8)));
typedef float f32x4  __attribute__((ext_vector_type(4)));

__device__ inline short f2bf(float f) {
    unsigned u = __builtin_bit_cast(unsigned, f);
    u += 0x7fff + ((u >> 16) & 1);            // RNE
    return (short)(u >> 16);
}
__device__ inline float bf2f(short s) {
    unsigned u = ((unsigned)(unsigned short)s) << 16;
    return __builtin_bit_cast(float, u);
}

// ---- weight pack for mfma_f32_16x16x32_bf16 A-operand, gamma folded in ----
// A-frag: lane l holds A[row=l&15][k = 8*(l>>4)+e], e=0..7 contiguous.
// layout: [conv][kb=4][t=9][h=2][lane=64][e=8], co = h*16+(l&15), cin = kb*32+8*(l>>4)+e
__global__ __launch_bounds__(256)
void pack_weights(const float* __restrict__ wR, const float* __restrict__ wH,
                  const float* __restrict__ rg, const float* __restrict__ hg,
                  short* __restrict__ wpack) {
    int id = blockIdx.x * 256 + threadIdx.x;   // 2*4*9*2*64*8 = 73728
    if (id >= 73728) return;
    int e    = id & 7;
    int lane = (id >> 3) & 63;
    int h    = (id >> 9) & 1;
    int t    = (id >> 10) % 9;
    int kb   = ((id >> 10) / 9) & 3;
    int conv = id / 36864;
    int co   = h * 16 + (lane & 15);
    int cin  = kb * 32 + (lane >> 4) * 8 + e;
    const float* w = conv ? wH : wR;
    const float* g = conv ? hg : rg;
    wpack[id] = f2bf(w[(co * 128 + cin) * 9 + t] * g[cin >> 5]);
}

// ---- NCHW f32 -> NHWC bf16 "combined" image: [n][y][x][cc=64] ----
// cc 0..15: xrgb[16+cc] | 16..31: yhsi[cc] | 32..47: xrgb[cc-32] | 48..63: yhsi[cc-48]
// (first 32 = conv0 source channels AND conv0 residual; last 32 = conv1's)
__global__ __launch_bounds__(256)
void nchw2nhwc(const float* __restrict__ xrgb, const float* __restrict__ yhsi,
               short* __restrict__ cmb) {
    int wave = threadIdx.x >> 6, lane = threadIdx.x & 63;
    if (lane >= 60) return;
    int y = blockIdx.y * 4 + wave;
    int x = blockIdx.x * 60 + lane;
    int n = blockIdx.z;
    const float* xb = xrgb + n * 32 * HW + y * 300 + x;
    const float* yb = yhsi + n * 32 * HW + y * 300 + x;
    short* dst = (short*)(cmb + ((size_t)n * HW + y * 300 + x) * 64);
    #pragma unroll
    for (int q = 0; q < 8; ++q) {
        short8 v;
        #pragma unroll
        for (int e = 0; e < 8; ++e) {
            int cc = q * 8 + e;
            const float* s;
            if (cc < 16)      s = xb + (16 + cc) * HW;
            else if (cc < 32) s = yb + cc * HW;
            else if (cc < 48) s = xb + (cc - 32) * HW;
            else              s = yb + (cc - 48) * HW;
            v[e] = f2bf(*s);
        }
        *(short8*)(dst + q * 8) = v;
    }
}

// ---- conv: 8x16 tile, halo 10x18, both convs in grid.z, 3 blocks/CU ----
__global__ __launch_bounds__(256, 3)
void conv_mfma(const short* __restrict__ combined, const short* __restrict__ wpack,
               const int* __restrict__ corr,
               const float* __restrict__ bR, const float* __restrict__ bH,
               float* __restrict__ out) {
    __shared__ alignas(16) char lds[180 * 256];   // 46080 B: 10x18 px * 4 slots * 64B
    int tile = blockIdx.x;
    int n = blockIdx.y;
    int conv = blockIdx.z;
    int ty = tile / 19, tx = tile - ty * 19;
    int y0 = ty * 8, x0 = tx * 16;
    int tid = threadIdx.x;

    const short* cmb = combined + (size_t)n * HW * 64;
    const short* wp  = wpack + conv * 36864;
    int wave = tid >> 6, lane = tid & 63;
    int l15 = lane & 15, lh = lane >> 4;

    // preload kb=0 A-frags before the barrier (global, independent of LDS)
    short8 af[9][2];
    #pragma unroll
    for (int t = 0; t < 9; ++t) {
        af[t][0] = *(const short8*)(wp + (((0 * 9 + t) * 2 + 0) * 64 + lane) * 8);
        af[t][1] = *(const short8*)(wp + (((0 * 9 + t) * 2 + 1) * 64 + lane) * 8);
    }

    // stage halo, k-major piece order: wave reads 64 consecutive halo px of one slot
    for (int p = tid; p < 720; p += 256) {
        int k = p / 180, pix = p - k * 180;
        int hr = pix / 18, hc = pix - hr * 18;
        int gy = y0 + hr - 1, gx = x0 + hc - 1;
        short8 v0 = {0,0,0,0,0,0,0,0}, v1 = v0, v2 = v0, v3 = v0;
        if (gy >= 0 && gy < 300 && gx >= 0 && gx < 300) {
            int pr = gy / 5, pc = gx / 5;
            int j  = pr * 60 + pc;
            int jp = (k == 0) ? j : corr[(n * 3600 + j) * 4 + k];
            int soff = ((jp / 60) * 5 + (gy - pr * 5)) * 300 + (jp % 60) * 5 + (gx - pc * 5);
            const short8* s = (const short8*)(cmb + (size_t)soff * 64 + conv * 32);
            v0 = s[0]; v1 = s[1]; v2 = s[2]; v3 = s[3];
        }
        int base = pix * 256 + k * 64;
        int swz  = (hc & 7) << 4;
        *(short8*)(lds + ((base +  0) ^ swz)) = v0;
        *(short8*)(lds + ((base + 16) ^ swz)) = v1;
        *(short8*)(lds + ((base + 32) ^ swz)) = v2;
        *(short8*)(lds + ((base + 48) ^ swz)) = v3;
    }
    __syncthreads();

    f32x4 acc[2][2];
    #pragma unroll
    for (int g = 0; g < 2; ++g)
        #pragma unroll
        for (int h = 0; h < 2; ++h)
            acc[g][h] = (f32x4){0.f, 0.f, 0.f, 0.f};

    #pragma unroll
    for (int kb = 0; kb < 4; ++kb) {
        short8 an[9][2];
        if (kb < 3) {
            #pragma unroll
            for (int t = 0; t < 9; ++t) {
                an[t][0] = *(const short8*)(wp + ((((kb + 1) * 9 + t) * 2 + 0) * 64 + lane) * 8);
                an[t][1] = *(const short8*)(wp + ((((kb + 1) * 9 + t) * 2 + 1) * 64 + lane) * 8);
            }
        }
        #pragma unroll
        for (int t = 0; t < 9; ++t) {
            int dy = t / 3 - 1, dx = t % 3 - 1;
            #pragma unroll
            for (int g = 0; g < 2; ++g) {
                int r  = wave * 2 + g;
                int hr = r + dy + 1;
                int hc = l15 + dx + 1;
                int lin = (hr * 18 + hc) * 256 + kb * 64 + lh * 16;
                short8 b = *(const short8*)(lds + (lin ^ ((hc & 7) << 4)));
                acc[g][0] = __builtin_amdgcn_mfma_f32_16x16x32_bf16(af[t][0], b, acc[g][0], 0, 0, 0);
                acc[g][1] = __builtin_amdgcn_mfma_f32_16x16x32_bf16(af[t][1], b, acc[g][1], 0, 0, 0);
            }
        }
        if (kb < 3) {
            #pragma unroll
            for (int t = 0; t < 9; ++t) {
                af[t][0] = an[t][0];
                af[t][1] = an[t][1];
            }
        }
    }

    // epilogue: residual+bias from cmb (contiguous 64B per lane, bf16)
    const float* bias = conv ? bH : bR;
    #pragma unroll
    for (int g = 0; g < 2; ++g) {
        int gy = y0 + wave * 2 + g;
        int gx = x0 + l15;
        if (gy < 300 && gx < 300) {
            int pixo = gy * 300 + gx;
            const short* resp = cmb + (size_t)pixo * 64 + conv * 32;
            short8 r0 = *(const short8*)(resp);
            short8 r1 = *(const short8*)(resp + 8);
            short8 r2 = *(const short8*)(resp + 16);
            short8 r3 = *(const short8*)(resp + 24);
            #pragma unroll
            for (int h = 0; h < 2; ++h) {
                #pragma unroll
                for (int reg = 0; reg < 4; ++reg) {
                    int co = h * 16 + lh * 4 + reg;
                    int q = co >> 3, e = co & 7;
                    float res = bf2f(q == 0 ? r0[e] : q == 1 ? r1[e] : q == 2 ? r2[e] : r3[e]);
                    out[conv * OUT_HALF + (n * 32 + co) * HW + pixo] = acc[g][h][reg] + bias[co] + res;
                }
            }
        }
    }
}

// ---- fallback (round-1 kernel) if ws too small ----
__global__ __launch_bounds__(256)
void fused_gather_conv(const float* __restrict__ xrgb, const float* __restrict__ yhsi,
                       const int* __restrict__ corr, const float* __restrict__ rgb_gamma,
                       const float* __restrict__ hsi_gamma, const float* __restrict__ wR,
                       const float* __restrict__ bR, const float* __restrict__ wH,
                       const float* __restrict__ bH, float* __restrict__ out) {
    int tid = blockIdx.x * blockDim.x + threadIdx.x;
    if (tid >= 4 * HW) return;
    int n = tid / HW, pix = tid - n * HW;
    int y = pix / 300, x = pix - y * 300;
    const int* idx = corr + n * (3600 * 4);
    const float* xb = xrgb + n * (32 * HW);
    const float* yb = yhsi + n * (32 * HW);
    float accR[32], accH[32];
    #pragma unroll
    for (int i = 0; i < 32; ++i) { accR[i] = 0.f; accH[i] = 0.f; }
    for (int k = 0; k < 4; ++k) {
        float gr = rgb_gamma[k], gh = hsi_gamma[k];
        int off[9];
        #pragma unroll
        for (int t = 0; t < 9; ++t) {
            int dy = t / 3 - 1, dx = t % 3 - 1;
            int yy = y + dy, xx = x + dx;
            int o = -1;
            if (yy >= 0 && yy < 300 && xx >= 0 && xx < 300) {
                int pr = yy / 5, pc = xx / 5;
                int j = pr * 60 + pc;
                int jp = (k == 0) ? j : idx[j * 4 + k];
                o = ((jp / 60) * 5 + (yy - pr * 5)) * 300 + (jp % 60) * 5 + (xx - pc * 5);
            }
            off[t] = o;
        }
        for (int c = 0; c < 32; ++c) {
            const float* srcR = (c < 16) ? (xb + (16 + c) * HW) : (yb + c * HW);
            const float* srcH = (c < 16) ? (xb + c * HW) : (yb + (c - 16) * HW);
            float vr[9], vh[9];
            #pragma unroll
            for (int t = 0; t < 9; ++t) {
                bool vld = off[t] >= 0;
                vr[t] = vld ? gr * srcR[off[t]] : 0.f;
                vh[t] = vld ? gh * srcH[off[t]] : 0.f;
            }
            const float* wRp = wR + (k * 32 + c) * 9;
            const float* wHp = wH + (k * 32 + c) * 9;
            #pragma unroll
            for (int t = 0; t < 9; ++t)
                #pragma unroll
                for (int co = 0; co < 32; ++co) {
                    accR[co] = fmaf(vr[t], wRp[co * 1152 + t], accR[co]);
                    accH[co] = fmaf(vh[t], wHp[co * 1152 + t], accH[co]);
                }
        }
    }
    #pragma unroll
    for (int co = 0; co < 32; ++co) {
        float resR = (co < 16) ? xb[(16 + co) * HW + pix] : yb[co * HW + pix];
        float resH = (co < 16) ? xb[co * HW + pix] : yb[(co - 16) * HW + pix];
        out[(n * 32 + co) * HW + pix]            = accR[co] + bR[co] + resR;
        out[OUT_HALF + (n * 32 + co) * HW + pix] = accH[co] + bH[co] + resH;
    }
}

extern "C" void kernel_launch(void* const* d_in, const int* in_sizes, int n_in,
                              void* d_out, int out_size, void* d_ws, size_t ws_size,
                              hipStream_t stream) {
    const float* xrgb = (const float*)d_in[0];
    const float* yhsi = (const float*)d_in[1];
    const int*   corr = (const int*)d_in[2];
    const float* rg   = (const float*)d_in[3];
    const float* hg   = (const float*)d_in[4];
    const float* wR   = (const float*)d_in[5];
    const float* bR   = (const float*)d_in[6];
    const float* wH   = (const float*)d_in[7];
    const float* bH   = (const float*)d_in[8];
    float* out = (float*)d_out;

    if (ws_size >= WS_NEED) {
        short* cmb   = (short*)d_ws;
        short* wpack = (short*)((char*)d_ws + WPACK_OFF);
        hipLaunchKernelGGL(pack_weights, dim3(288), dim3(256), 0, stream, wR, wH, rg, hg, wpack);
        hipLaunchKernelGGL(nchw2nhwc, dim3(5, 75, 4), dim3(256), 0, stream, xrgb, yhsi, cmb);
        hipLaunchKernelGGL(conv_mfma, dim3(722, 4, 2), dim3(256), 0, stream,
                           cmb, wpack, corr, bR, bH, out);
    } else {
        int total = 4 * HW;
        hipLaunchKernelGGL(fused_gather_conv, dim3((total + 255) / 256), dim3(256), 0, stream,
                           xrgb, yhsi, corr, rg, hg, wR, bR, wH, bH, out);
    }
}

// Round 8
// 176.616 us; speedup vs baseline: 10.2773x; 1.0213x over previous
//
#include <hip/hip_runtime.h>

// N=4, C=32(n_feats), H=W=300, P=5 fixed by setup_inputs.
#define HW        90000
#define OUT_HALF  11520000
#define WPACK_OFF  46080000ull
#define WS_NEED    (46080000ull + 147456ull)

typedef short short8 __attribute__((ext_vector_type(8)));
typedef float f32x4  __attribute__((ext_vector_type(4)));

__device__ inline short f2bf(float f) {
    unsigned u = __builtin_bit_cast(unsigned, f);
    u += 0x7fff + ((u >> 16) & 1);            // RNE
    return (short)(u >> 16);
}
__device__ inline float bf2f(short s) {
    unsigned u = ((unsigned)(unsigned short)s) << 16;
    return __builtin_bit_cast(float, u);
}

// ---- weight pack for mfma_f32_16x16x32_bf16 A-operand, gamma folded in ----
// A-frag: lane l holds A[row=l&15][k = 8*(l>>4)+e], e=0..7 contiguous.
// layout: [conv][kb=4][t=9][h=2][lane=64][e=8], co = h*16+(l&15), cin = kb*32+8*(l>>4)+e
__global__ __launch_bounds__(256)
void pack_weights(const float* __restrict__ wR, const float* __restrict__ wH,
                  const float* __restrict__ rg, const float* __restrict__ hg,
                  short* __restrict__ wpack) {
    int id = blockIdx.x * 256 + threadIdx.x;   // 2*4*9*2*64*8 = 73728
    if (id >= 73728) return;
    int e    = id & 7;
    int lane = (id >> 3) & 63;
    int h    = (id >> 9) & 1;
    int t    = (id >> 10) % 9;
    int kb   = ((id >> 10) / 9) & 3;
    int conv = id / 36864;
    int co   = h * 16 + (lane & 15);
    int cin  = kb * 32 + (lane >> 4) * 8 + e;
    const float* w = conv ? wH : wR;
    const float* g = conv ? hg : rg;
    wpack[id] = f2bf(w[(co * 128 + cin) * 9 + t] * g[cin >> 5]);
}

// ---- NCHW f32 -> NHWC bf16 "combined" image: [n][y][x][cc=64] ----
// cc 0..15: xrgb[16+cc] | 16..31: yhsi[cc] | 32..47: xrgb[cc-32] | 48..63: yhsi[cc-48]
__global__ __launch_bounds__(256)
void nchw2nhwc(const float* __restrict__ xrgb, const float* __restrict__ yhsi,
               short* __restrict__ cmb) {
    int wave = threadIdx.x >> 6, lane = threadIdx.x & 63;
    if (lane >= 60) return;
    int y = blockIdx.y * 4 + wave;
    int x = blockIdx.x * 60 + lane;
    int n = blockIdx.z;
    const float* xb = xrgb + n * 32 * HW + y * 300 + x;
    const float* yb = yhsi + n * 32 * HW + y * 300 + x;
    short* dst = (short*)(cmb + ((size_t)n * HW + y * 300 + x) * 64);
    #pragma unroll
    for (int q = 0; q < 8; ++q) {
        short8 v;
        #pragma unroll
        for (int e = 0; e < 8; ++e) {
            int cc = q * 8 + e;
            const float* s;
            if (cc < 16)      s = xb + (16 + cc) * HW;
            else if (cc < 32) s = yb + cc * HW;
            else if (cc < 48) s = xb + (cc - 32) * HW;
            else              s = yb + (cc - 48) * HW;
            v[e] = f2bf(*s);
        }
        *(short8*)(dst + q * 8) = v;
    }
}

// ---- conv: 8x16 tile, halo 10x18, per-k double-buffered LDS (23 KB), 6 blk/CU ----
__global__ __launch_bounds__(256, 8)
void conv_mfma(const short* __restrict__ combined, const short* __restrict__ wpack,
               const int* __restrict__ corr,
               const float* __restrict__ bR, const float* __restrict__ bH,
               float* __restrict__ out) {
    __shared__ alignas(16) char lds[2][180 * 64];   // 23040 B total
    int tile = blockIdx.x;
    int n = blockIdx.y;
    int conv = blockIdx.z;
    int ty = tile / 19, tx = tile - ty * 19;
    int y0 = ty * 8, x0 = tx * 16;
    int tid = threadIdx.x;

    const short* cmb = combined + (size_t)n * HW * 64;
    const short* wp  = wpack + conv * 36864;

    // staging statics: thread tid<180 owns halo pixel tid for all 4 slots
    bool stager = tid < 180;
    int sj = 0, sintra = 0;
    const int* scr = corr;    // dummy init
    bool svalid = false;
    if (stager) {
        int hr = tid / 18, hc = tid - hr * 18;
        int gy = y0 + hr - 1, gx = x0 + hc - 1;
        svalid = (gy >= 0 && gy < 300 && gx >= 0 && gx < 300);
        if (svalid) {
            int pr = gy / 5, pc = gx / 5;
            sj = pr * 60 + pc;
            sintra = (gy - pr * 5) * 300 + (gx - pc * 5);
            scr = corr + (n * 3600 + sj) * 4;
        }
    }

    #define STAGE(buf, k)                                                        \
        do {                                                                     \
            short8 v0 = {0,0,0,0,0,0,0,0}, v1 = v0, v2 = v0, v3 = v0;            \
            if (svalid) {                                                        \
                int jp = ((k) == 0) ? sj : scr[(k)];                             \
                int soff = (jp / 60) * 1500 + (jp % 60) * 5 + sintra;            \
                const short8* s = (const short8*)(cmb + (size_t)soff * 64 + conv * 32); \
                v0 = s[0]; v1 = s[1]; v2 = s[2]; v3 = s[3];                      \
            }                                                                    \
            short8* d = (short8*)(lds[(buf)] + tid * 64);                        \
            d[0] = v0; d[1] = v1; d[2] = v2; d[3] = v3;                          \
        } while (0)

    if (stager) STAGE(0, 0);
    __syncthreads();

    int wave = tid >> 6, lane = tid & 63;
    int l15 = lane & 15, lh = lane >> 4;

    f32x4 acc[2][2];
    #pragma unroll
    for (int g = 0; g < 2; ++g)
        #pragma unroll
        for (int h = 0; h < 2; ++h)
            acc[g][h] = (f32x4){0.f, 0.f, 0.f, 0.f};

    #pragma unroll
    for (int kb = 0; kb < 4; ++kb) {
        if (kb < 3 && stager) STAGE((kb + 1) & 1, kb + 1);
        const char* base = lds[kb & 1];
        #pragma unroll
        for (int t = 0; t < 9; ++t) {
            int dy = t / 3 - 1, dx = t % 3 - 1;
            short8 a0 = *(const short8*)(wp + (((kb * 9 + t) * 2 + 0) * 64 + lane) * 8);
            short8 a1 = *(const short8*)(wp + (((kb * 9 + t) * 2 + 1) * 64 + lane) * 8);
            #pragma unroll
            for (int g = 0; g < 2; ++g) {
                int hr = wave * 2 + g + dy + 1;
                int hc = l15 + dx + 1;
                short8 b = *(const short8*)(base + (hr * 18 + hc) * 64 + lh * 16);
                acc[g][0] = __builtin_amdgcn_mfma_f32_16x16x32_bf16(a0, b, acc[g][0], 0, 0, 0);
                acc[g][1] = __builtin_amdgcn_mfma_f32_16x16x32_bf16(a1, b, acc[g][1], 0, 0, 0);
            }
        }
        __syncthreads();
    }

    // epilogue: residual+bias from cmb (contiguous 64B per lane, bf16)
    const float* bias = conv ? bH : bR;
    #pragma unroll
    for (int g = 0; g < 2; ++g) {
        int gy = y0 + wave * 2 + g;
        int gx = x0 + l15;
        if (gy < 300 && gx < 300) {
            int pixo = gy * 300 + gx;
            const short* resp = cmb + (size_t)pixo * 64 + conv * 32;
            short8 r0 = *(const short8*)(resp);
            short8 r1 = *(const short8*)(resp + 8);
            short8 r2 = *(const short8*)(resp + 16);
            short8 r3 = *(const short8*)(resp + 24);
            #pragma unroll
            for (int h = 0; h < 2; ++h) {
                #pragma unroll
                for (int reg = 0; reg < 4; ++reg) {
                    int co = h * 16 + lh * 4 + reg;
                    int q = co >> 3, e = co & 7;
                    float res = bf2f(q == 0 ? r0[e] : q == 1 ? r1[e] : q == 2 ? r2[e] : r3[e]);
                    out[conv * OUT_HALF + (n * 32 + co) * HW + pixo] = acc[g][h][reg] + bias[co] + res;
                }
            }
        }
    }
    #undef STAGE
}

// ---- fallback (round-1 kernel) if ws too small ----
__global__ __launch_bounds__(256)
void fused_gather_conv(const float* __restrict__ xrgb, const float* __restrict__ yhsi,
                       const int* __restrict__ corr, const float* __restrict__ rgb_gamma,
                       const float* __restrict__ hsi_gamma, const float* __restrict__ wR,
                       const float* __restrict__ bR, const float* __restrict__ wH,
                       const float* __restrict__ bH, float* __restrict__ out) {
    int tid = blockIdx.x * blockDim.x + threadIdx.x;
    if (tid >= 4 * HW) return;
    int n = tid / HW, pix = tid - n * HW;
    int y = pix / 300, x = pix - y * 300;
    const int* idx = corr + n * (3600 * 4);
    const float* xb = xrgb + n * (32 * HW);
    const float* yb = yhsi + n * (32 * HW);
    float accR[32], accH[32];
    #pragma unroll
    for (int i = 0; i < 32; ++i) { accR[i] = 0.f; accH[i] = 0.f; }
    for (int k = 0; k < 4; ++k) {
        float gr = rgb_gamma[k], gh = hsi_gamma[k];
        int off[9];
        #pragma unroll
        for (int t = 0; t < 9; ++t) {
            int dy = t / 3 - 1, dx = t % 3 - 1;
            int yy = y + dy, xx = x + dx;
            int o = -1;
            if (yy >= 0 && yy < 300 && xx >= 0 && xx < 300) {
                int pr = yy / 5, pc = xx / 5;
                int j = pr * 60 + pc;
                int jp = (k == 0) ? j : idx[j * 4 + k];
                o = ((jp / 60) * 5 + (yy - pr * 5)) * 300 + (jp % 60) * 5 + (xx - pc * 5);
            }
            off[t] = o;
        }
        for (int c = 0; c < 32; ++c) {
            const float* srcR = (c < 16) ? (xb + (16 + c) * HW) : (yb + c * HW);
            const float* srcH = (c < 16) ? (xb + c * HW) : (yb + (c - 16) * HW);
            float vr[9], vh[9];
            #pragma unroll
            for (int t = 0; t < 9; ++t) {
                bool vld = off[t] >= 0;
                vr[t] = vld ? gr * srcR[off[t]] : 0.f;
                vh[t] = vld ? gh * srcH[off[t]] : 0.f;
            }
            const float* wRp = wR + (k * 32 + c) * 9;
            const float* wHp = wH + (k * 32 + c) * 9;
            #pragma unroll
            for (int t = 0; t < 9; ++t)
                #pragma unroll
                for (int co = 0; co < 32; ++co) {
                    accR[co] = fmaf(vr[t], wRp[co * 1152 + t], accR[co]);
                    accH[co] = fmaf(vh[t], wHp[co * 1152 + t], accH[co]);
                }
        }
    }
    #pragma unroll
    for (int co = 0; co < 32; ++co) {
        float resR = (co < 16) ? xb[(16 + co) * HW + pix] : yb[co * HW + pix];
        float resH = (co < 16) ? xb[co * HW + pix] : yb[(co - 16) * HW + pix];
        out[(n * 32 + co) * HW + pix]            = accR[co] + bR[co] + resR;
        out[OUT_HALF + (n * 32 + co) * HW + pix] = accH[co] + bH[co] + resH;
    }
}

extern "C" void kernel_launch(void* const* d_in, const int* in_sizes, int n_in,
                              void* d_out, int out_size, void* d_ws, size_t ws_size,
                              hipStream_t stream) {
    const float* xrgb = (const float*)d_in[0];
    const float* yhsi = (const float*)d_in[1];
    const int*   corr = (const int*)d_in[2];
    const float* rg   = (const float*)d_in[3];
    const float* hg   = (const float*)d_in[4];
    const float* wR   = (const float*)d_in[5];
    const float* bR   = (const float*)d_in[6];
    const float* wH   = (const float*)d_in[7];
    const float* bH   = (const float*)d_in[8];
    float* out = (float*)d_out;

    if (ws_size >= WS_NEED) {
        short* cmb   = (short*)d_ws;
        short* wpack = (short*)((char*)d_ws + WPACK_OFF);
        hipLaunchKernelGGL(pack_weights, dim3(288), dim3(256), 0, stream, wR, wH, rg, hg, wpack);
        hipLaunchKernelGGL(nchw2nhwc, dim3(5, 75, 4), dim3(256), 0, stream, xrgb, yhsi, cmb);
        hipLaunchKernelGGL(conv_mfma, dim3(722, 4, 2), dim3(256), 0, stream,
                           cmb, wpack, corr, bR, bH, out);
    } else {
        int total = 4 * HW;
        hipLaunchKernelGGL(fused_gather_conv, dim3((total + 255) / 256), dim3(256), 0, stream,
                           xrgb, yhsi, corr, rg, hg, wR, bR, wH, bH, out);
    }
}

// Round 9
// 147.980 us; speedup vs baseline: 12.2660x; 1.1935x over previous
//
#include <hip/hip_runtime.h>

// N=4, C=32(n_feats), H=W=300, P=5 fixed by setup_inputs.
#define HW        90000
#define OUT_HALF  11520000
#define CPLANE    11520000ull            // shorts per conv plane (4*90000*32)
#define WPACK_OFF  46080000ull           // bytes: 2 planes * 23.04 MB
#define WS_NEED    (46080000ull + 147456ull)

typedef short short8 __attribute__((ext_vector_type(8)));
typedef float f32x4  __attribute__((ext_vector_type(4)));

__device__ inline short f2bf(float f) {
    unsigned u = __builtin_bit_cast(unsigned, f);
    u += 0x7fff + ((u >> 16) & 1);            // RNE
    return (short)(u >> 16);
}
__device__ inline float bf2f(short s) {
    unsigned u = ((unsigned)(unsigned short)s) << 16;
    return __builtin_bit_cast(float, u);
}

// ---- weight pack for mfma_f32_16x16x32_bf16 A-operand, gamma folded in ----
// A-frag: lane l holds A[row=l&15][k = 8*(l>>4)+e], e=0..7 contiguous.
// layout: [conv][kb=4][t=9][h=2][lane=64][e=8], co = h*16+(l&15), cin = kb*32+8*(l>>4)+e
__global__ __launch_bounds__(256)
void pack_weights(const float* __restrict__ wR, const float* __restrict__ wH,
                  const float* __restrict__ rg, const float* __restrict__ hg,
                  short* __restrict__ wpack) {
    int id = blockIdx.x * 256 + threadIdx.x;   // 2*4*9*2*64*8 = 73728
    if (id >= 73728) return;
    int e    = id & 7;
    int lane = (id >> 3) & 63;
    int h    = (id >> 9) & 1;
    int t    = (id >> 10) % 9;
    int kb   = ((id >> 10) / 9) & 3;
    int conv = id / 36864;
    int co   = h * 16 + (lane & 15);
    int cin  = kb * 32 + (lane >> 4) * 8 + e;
    const float* w = conv ? wH : wR;
    const float* g = conv ? hg : rg;
    wpack[id] = f2bf(w[(co * 128 + cin) * 9 + t] * g[cin >> 5]);
}

// ---- NCHW f32 -> per-conv NHWC bf16 planes: cmb[conv][n][y][x][32ch] ----
// conv0 ch c: c<16 -> xrgb[16+c], else yhsi[c];  conv1 ch c: c<16 -> xrgb[c], else yhsi[c-16]
__global__ __launch_bounds__(256)
void nchw2nhwc(const float* __restrict__ xrgb, const float* __restrict__ yhsi,
               short* __restrict__ cmb) {
    int wave = threadIdx.x >> 6, lane = threadIdx.x & 63;
    if (lane >= 60) return;
    int y = blockIdx.y * 4 + wave;
    int x = blockIdx.x * 60 + lane;
    int n = blockIdx.z;
    const float* xb = xrgb + n * 32 * HW + y * 300 + x;
    const float* yb = yhsi + n * 32 * HW + y * 300 + x;
    size_t pxo = ((size_t)n * HW + y * 300 + x) * 32;
    short* d0 = cmb + pxo;
    short* d1 = cmb + CPLANE + pxo;
    #pragma unroll
    for (int q = 0; q < 4; ++q) {
        short8 v0, v1;
        #pragma unroll
        for (int e = 0; e < 8; ++e) {
            int c = q * 8 + e;
            v0[e] = f2bf((c < 16) ? xb[(16 + c) * HW] : yb[c * HW]);
            v1[e] = f2bf((c < 16) ? xb[c * HW] : yb[(c - 16) * HW]);
        }
        *(short8*)(d0 + q * 8) = v0;
        *(short8*)(d1 + q * 8) = v1;
    }
}

// ---- conv: 12x16 tile, halo 14x18=252px, dbuf 31.5KB LDS, swizzled, g=3 ----
__global__ __launch_bounds__(256, 5)
void conv_mfma(const short* __restrict__ cmb_all, const short* __restrict__ wpack,
               const int* __restrict__ corr,
               const float* __restrict__ bR, const float* __restrict__ bH,
               float* __restrict__ out) {
    __shared__ alignas(16) char lds[2][16128];   // 2 x 252px x 64B
    int tile = blockIdx.x;
    int n = blockIdx.y;
    int conv = blockIdx.z;
    int ty = tile / 19, tx = tile - ty * 19;
    int y0 = ty * 12, x0 = tx * 16;
    int tid = threadIdx.x;

    const short* cmb = cmb_all + conv * CPLANE + (size_t)n * HW * 32;
    const short* wp  = wpack + conv * 36864;

    // stager: thread tid<252 owns halo pixel tid across all 4 slots
    bool stager = tid < 252;
    int sj = 0, sintra = 0;
    const int* scr = corr;
    bool svalid = false;
    if (stager) {
        int hr = tid / 18, hc = tid - hr * 18;
        int gy = y0 + hr - 1, gx = x0 + hc - 1;
        svalid = (gy >= 0 && gy < 300 && gx >= 0 && gx < 300);
        if (svalid) {
            int pr = gy / 5, pc = gx / 5;
            sj = pr * 60 + pc;
            sintra = (gy - pr * 5) * 300 + (gx - pc * 5);
            scr = corr + (n * 3600 + sj) * 4;
        }
    }
    int swz = (tid & 7) << 4;

    #define STAGE(buf, k)                                                        \
        do {                                                                     \
            short8 v0 = {0,0,0,0,0,0,0,0}, v1 = v0, v2 = v0, v3 = v0;            \
            if (svalid) {                                                        \
                int jp = ((k) == 0) ? sj : scr[(k)];                             \
                int soff = (jp / 60) * 1500 + (jp % 60) * 5 + sintra;            \
                const short8* s = (const short8*)(cmb + (size_t)soff * 32);      \
                v0 = s[0]; v1 = s[1]; v2 = s[2]; v3 = s[3];                      \
            }                                                                    \
            char* d = lds[(buf)];                                                \
            int b0 = tid * 64;                                                   \
            *(short8*)(d + ((b0 +  0) ^ swz)) = v0;                              \
            *(short8*)(d + ((b0 + 16) ^ swz)) = v1;                              \
            *(short8*)(d + ((b0 + 32) ^ swz)) = v2;                              \
            *(short8*)(d + ((b0 + 48) ^ swz)) = v3;                              \
        } while (0)

    if (stager) STAGE(0, 0);
    __syncthreads();

    int wave = tid >> 6, lane = tid & 63;
    int l15 = lane & 15, lh = lane >> 4;

    f32x4 acc[3][2];
    #pragma unroll
    for (int g = 0; g < 3; ++g)
        #pragma unroll
        for (int h = 0; h < 2; ++h)
            acc[g][h] = (f32x4){0.f, 0.f, 0.f, 0.f};

    #pragma unroll
    for (int kb = 0; kb < 4; ++kb) {
        if (kb < 3 && stager) STAGE((kb + 1) & 1, kb + 1);
        const char* base = lds[kb & 1];
        #pragma unroll
        for (int t = 0; t < 9; ++t) {
            int dy = t / 3 - 1, dx = t % 3 - 1;
            short8 a0 = *(const short8*)(wp + (((kb * 9 + t) * 2 + 0) * 64 + lane) * 8);
            short8 a1 = *(const short8*)(wp + (((kb * 9 + t) * 2 + 1) * 64 + lane) * 8);
            #pragma unroll
            for (int g = 0; g < 3; ++g) {
                int hp = (wave * 3 + g + dy + 1) * 18 + (l15 + dx + 1);
                short8 b = *(const short8*)(base + ((hp * 64 + lh * 16) ^ ((hp & 7) << 4)));
                acc[g][0] = __builtin_amdgcn_mfma_f32_16x16x32_bf16(a0, b, acc[g][0], 0, 0, 0);
                acc[g][1] = __builtin_amdgcn_mfma_f32_16x16x32_bf16(a1, b, acc[g][1], 0, 0, 0);
            }
        }
        __syncthreads();
    }

    // epilogue: residual+bias from cmb (dense 64B per lane, bf16)
    const float* bias = conv ? bH : bR;
    #pragma unroll
    for (int g = 0; g < 3; ++g) {
        int gy = y0 + wave * 3 + g;          // always < 300 (25*12=300)
        int gx = x0 + l15;
        if (gx < 300) {
            int pixo = gy * 300 + gx;
            const short* resp = cmb + (size_t)pixo * 32;
            short8 r0 = *(const short8*)(resp);
            short8 r1 = *(const short8*)(resp + 8);
            short8 r2 = *(const short8*)(resp + 16);
            short8 r3 = *(const short8*)(resp + 24);
            #pragma unroll
            for (int h = 0; h < 2; ++h) {
                #pragma unroll
                for (int reg = 0; reg < 4; ++reg) {
                    int co = h * 16 + lh * 4 + reg;
                    int q = co >> 3, e = co & 7;
                    float res = bf2f(q == 0 ? r0[e] : q == 1 ? r1[e] : q == 2 ? r2[e] : r3[e]);
                    out[conv * OUT_HALF + (n * 32 + co) * HW + pixo] = acc[g][h][reg] + bias[co] + res;
                }
            }
        }
    }
    #undef STAGE
}

// ---- fallback (round-1 kernel) if ws too small ----
__global__ __launch_bounds__(256)
void fused_gather_conv(const float* __restrict__ xrgb, const float* __restrict__ yhsi,
                       const int* __restrict__ corr, const float* __restrict__ rgb_gamma,
                       const float* __restrict__ hsi_gamma, const float* __restrict__ wR,
                       const float* __restrict__ bR, const float* __restrict__ wH,
                       const float* __restrict__ bH, float* __restrict__ out) {
    int tid = blockIdx.x * blockDim.x + threadIdx.x;
    if (tid >= 4 * HW) return;
    int n = tid / HW, pix = tid - n * HW;
    int y = pix / 300, x = pix - y * 300;
    const int* idx = corr + n * (3600 * 4);
    const float* xb = xrgb + n * (32 * HW);
    const float* yb = yhsi + n * (32 * HW);
    float accR[32], accH[32];
    #pragma unroll
    for (int i = 0; i < 32; ++i) { accR[i] = 0.f; accH[i] = 0.f; }
    for (int k = 0; k < 4; ++k) {
        float gr = rgb_gamma[k], gh = hsi_gamma[k];
        int off[9];
        #pragma unroll
        for (int t = 0; t < 9; ++t) {
            int dy = t / 3 - 1, dx = t % 3 - 1;
            int yy = y + dy, xx = x + dx;
            int o = -1;
            if (yy >= 0 && yy < 300 && xx >= 0 && xx < 300) {
                int pr = yy / 5, pc = xx / 5;
                int j = pr * 60 + pc;
                int jp = (k == 0) ? j : idx[j * 4 + k];
                o = ((jp / 60) * 5 + (yy - pr * 5)) * 300 + (jp % 60) * 5 + (xx - pc * 5);
            }
            off[t] = o;
        }
        for (int c = 0; c < 32; ++c) {
            const float* srcR = (c < 16) ? (xb + (16 + c) * HW) : (yb + c * HW);
            const float* srcH = (c < 16) ? (xb + c * HW) : (yb + (c - 16) * HW);
            float vr[9], vh[9];
            #pragma unroll
            for (int t = 0; t < 9; ++t) {
                bool vld = off[t] >= 0;
                vr[t] = vld ? gr * srcR[off[t]] : 0.f;
                vh[t] = vld ? gh * srcH[off[t]] : 0.f;
            }
            const float* wRp = wR + (k * 32 + c) * 9;
            const float* wHp = wH + (k * 32 + c) * 9;
            #pragma unroll
            for (int t = 0; t < 9; ++t)
                #pragma unroll
                for (int co = 0; co < 32; ++co) {
                    accR[co] = fmaf(vr[t], wRp[co * 1152 + t], accR[co]);
                    accH[co] = fmaf(vh[t], wHp[co * 1152 + t], accH[co]);
                }
        }
    }
    #pragma unroll
    for (int co = 0; co < 32; ++co) {
        float resR = (co < 16) ? xb[(16 + co) * HW + pix] : yb[co * HW + pix];
        float resH = (co < 16) ? xb[co * HW + pix] : yb[(co - 16) * HW + pix];
        out[(n * 32 + co) * HW + pix]            = accR[co] + bR[co] + resR;
        out[OUT_HALF + (n * 32 + co) * HW + pix] = accH[co] + bH[co] + resH;
    }
}

extern "C" void kernel_launch(void* const* d_in, const int* in_sizes, int n_in,
                              void* d_out, int out_size, void* d_ws, size_t ws_size,
                              hipStream_t stream) {
    const float* xrgb = (const float*)d_in[0];
    const float* yhsi = (const float*)d_in[1];
    const int*   corr = (const int*)d_in[2];
    const float* rg   = (const float*)d_in[3];
    const float* hg   = (const float*)d_in[4];
    const float* wR   = (const float*)d_in[5];
    const float* bR   = (const float*)d_in[6];
    const float* wH   = (const float*)d_in[7];
    const float* bH   = (const float*)d_in[8];
    float* out = (float*)d_out;

    if (ws_size >= WS_NEED) {
        short* cmb   = (short*)d_ws;
        short* wpack = (short*)((char*)d_ws + WPACK_OFF);
        hipLaunchKernelGGL(pack_weights, dim3(288), dim3(256), 0, stream, wR, wH, rg, hg, wpack);
        hipLaunchKernelGGL(nchw2nhwc, dim3(5, 75, 4), dim3(256), 0, stream, xrgb, yhsi, cmb);
        hipLaunchKernelGGL(conv_mfma, dim3(475, 4, 2), dim3(256), 0, stream,
                           cmb, wpack, corr, bR, bH, out);
    } else {
        int total = 4 * HW;
        hipLaunchKernelGGL(fused_gather_conv, dim3((total + 255) / 256), dim3(256), 0, stream,
                           xrgb, yhsi, corr, rg, hg, wR, bR, wH, bH, out);
    }
}